// Round 1
// 231.507 us; speedup vs baseline: 1.0522x; 1.0522x over previous
//
#include <hip/hip_runtime.h>
#include <math.h>

#define N_ROWS 131072
#define DIMS 64
#define K_CODES 512
#define ROWS_PER_BLOCK 64
#define NBLK (N_ROWS / ROWS_PER_BLOCK)  // 2048
#define XS_STRIDE 68                    // padded row stride (full-BW banked b128 reads)

// compile-time float4 component select (only valid under full unroll)
#define XQE(arr, d) ((((d)&3)==0) ? arr[(d)>>2].x : ((((d)&3)==1) ? arr[(d)>>2].y : ((((d)&3)==2) ? arr[(d)>>2].z : arr[(d)>>2].w)))

// ---------------- K0: zero bins + c2 (numpy pairwise, bitwise) + codebook transpose ----
// 64 blocks x 256. Block 0 additionally zeroes bins and computes c2.
// Transpose layout: cbT2[(k>>4)*1024 + d*16 + (k&15)]  — group-major [32][64][16]
// so a wave's 16-code group at dim d is one contiguous 64 B line (s_load_dwordx16).
__global__ __launch_bounds__(256) void vq_init(const float* __restrict__ codebook,
                                               int* __restrict__ bins,
                                               float* __restrict__ c2g,
                                               float* __restrict__ cbT2) {
  #pragma clang fp contract(off)
  const int t = threadIdx.x;
  const int b = blockIdx.x;
  if (b == 0) {
    for (int k = t; k < K_CODES; k += 256) bins[k] = 0;
    // numpy pairwise_sum, n=64: 8 accumulators over stride-8 lanes, then fixed tree.
    for (int k = t; k < K_CODES; k += 256) {
      const float* cr = codebook + k * DIMS;
      float r[8];
      #pragma unroll
      for (int j = 0; j < 8; ++j) r[j] = cr[j] * cr[j];
      for (int i = 8; i < 64; i += 8) {
        #pragma unroll
        for (int j = 0; j < 8; ++j) r[j] += cr[i + j] * cr[i + j];  // contract OFF: mul, add
      }
      c2g[k] = ((r[0] + r[1]) + (r[2] + r[3])) + ((r[4] + r[5]) + (r[6] + r[7]));
    }
  }
  // transpose slice: this block owns codes [b*8, b*8+8)
  for (int e = t; e < 512; e += 256) {
    const int k = b * 8 + (e >> 6);
    const int d = e & 63;
    cbT2[(k >> 4) * 1024 + d * 16 + (k & 15)] = codebook[k * DIMS + d];
  }
}

// ---------------- K1: fused argmin + gather + STE + loss partial -----------------------
// 2048 blocks x 256 threads. lane = row (64 rows/block, latent row in VGPRs).
// wave w owns codes [w*128, (w+1)*128) as 8 groups of 16; codebook values arrive via
// wave-uniform s_load_dwordx16 (scalar cache) -> inner loop is pure v_fmac (s,v,v).
// M[n,k] = sequential fmaf over d ascending (BLAS sgemm order, bitwise as before).
__global__ __launch_bounds__(256, 4) void vq_main(const float* __restrict__ latents,
                                                  const float* __restrict__ codebook,
                                                  const float* __restrict__ cbT2,
                                                  const float* __restrict__ c2g,
                                                  float* __restrict__ out_st,
                                                  float* __restrict__ out_codes,
                                                  int* __restrict__ bins,
                                                  double* __restrict__ loss_part) {
  #pragma clang fp contract(off)
  __shared__ __align__(16) float xs[ROWS_PER_BLOCK * XS_STRIDE];  // 17408 B
  __shared__ float mvv[4][64];
  __shared__ int   mii[4][64];
  const int t = threadIdx.x;
  const int lane = t & 63;
  const int w = __builtin_amdgcn_readfirstlane(t >> 6);  // wave id, provably uniform
  const int row0 = blockIdx.x * ROWS_PER_BLOCK;

  // stage 64-row latent tile coalesced -> padded LDS
  {
    const float4* src = (const float4*)(latents + (size_t)row0 * DIMS);
    #pragma unroll
    for (int p = 0; p < 4; ++p) {
      const int f = p * 256 + t;           // 0..1023
      const int r = f >> 4, q4 = f & 15;
      *(float4*)&xs[r * XS_STRIDE + q4 * 4] = src[f];
    }
  }
  __syncthreads();

  // own row -> registers (16 x b128; stride-68 rows = full-bandwidth bank pattern)
  float4 xq[16];
  #pragma unroll
  for (int d4 = 0; d4 < 16; ++d4) xq[d4] = *(const float4*)&xs[lane * XS_STRIDE + d4 * 4];

  // x2: numpy pairwise_sum in-lane (same values, same add order as before)
  float x2v;
  {
    float r[8];
    #pragma unroll
    for (int j = 0; j < 8; ++j) { const float v = XQE(xq, j); r[j] = v * v; }
    #pragma unroll
    for (int i = 1; i < 8; ++i) {
      #pragma unroll
      for (int j = 0; j < 8; ++j) { const float v = XQE(xq, i * 8 + j); r[j] += v * v; }
    }
    x2v = ((r[0] + r[1]) + (r[2] + r[3])) + ((r[4] + r[5]) + (r[6] + r[7]));
  }

  float m1 = __builtin_inff();
  int   i1 = 0x7fffffff;

  #pragma unroll 1
  for (int g = 0; g < 8; ++g) {
    const int kb = w * 128 + g * 16;                       // uniform
    const float4* gb = (const float4*)(cbT2 + (size_t)(w * 8 + g) * 1024);
    float acc[16];
    #pragma unroll
    for (int j = 0; j < 16; ++j) acc[j] = 0.f;

    #pragma unroll
    for (int d = 0; d < 64; ++d) {
      const float4 ca = gb[d * 4 + 0];   // uniform 64 B -> s_load_dwordx16
      const float4 cb = gb[d * 4 + 1];
      const float4 cc = gb[d * 4 + 2];
      const float4 cd = gb[d * 4 + 3];
      const float xd = XQE(xq, d);       // single fmaf chain per (row,code), d ascending
      acc[0]  = fmaf(xd, ca.x, acc[0]);
      acc[1]  = fmaf(xd, ca.y, acc[1]);
      acc[2]  = fmaf(xd, ca.z, acc[2]);
      acc[3]  = fmaf(xd, ca.w, acc[3]);
      acc[4]  = fmaf(xd, cb.x, acc[4]);
      acc[5]  = fmaf(xd, cb.y, acc[5]);
      acc[6]  = fmaf(xd, cb.z, acc[6]);
      acc[7]  = fmaf(xd, cb.w, acc[7]);
      acc[8]  = fmaf(xd, cc.x, acc[8]);
      acc[9]  = fmaf(xd, cc.y, acc[9]);
      acc[10] = fmaf(xd, cc.z, acc[10]);
      acc[11] = fmaf(xd, cc.w, acc[11]);
      acc[12] = fmaf(xd, cd.x, acc[12]);
      acc[13] = fmaf(xd, cd.y, acc[13]);
      acc[14] = fmaf(xd, cd.z, acc[14]);
      acc[15] = fmaf(xd, cd.w, acc[15]);
    }

    // d2 = (x2 - 2*M) + c2, each op one fp32 rounding; strict < keeps first (k ascending)
    const float4* c2p = (const float4*)(c2g + kb);
    const float4 e0 = c2p[0], e1 = c2p[1], e2 = c2p[2], e3 = c2p[3];
    float c2a[16];
    c2a[0]=e0.x; c2a[1]=e0.y; c2a[2]=e0.z; c2a[3]=e0.w;
    c2a[4]=e1.x; c2a[5]=e1.y; c2a[6]=e1.z; c2a[7]=e1.w;
    c2a[8]=e2.x; c2a[9]=e2.y; c2a[10]=e2.z; c2a[11]=e2.w;
    c2a[12]=e3.x; c2a[13]=e3.y; c2a[14]=e3.z; c2a[15]=e3.w;
    #pragma unroll
    for (int j = 0; j < 16; ++j) {
      const float tt = x2v - 2.0f * acc[j];
      const float s = tt + c2a[j];
      if (s < m1) { m1 = s; i1 = kb + j; }
    }
  }

  // cross-wave merge: waves hold disjoint ASCENDING code ranges -> strict < keeps first k
  mvv[w][lane] = m1;
  mii[w][lane] = i1;
  __syncthreads();

  if (w == 0) {
    float v = mvv[0][lane];
    int idx = mii[0][lane];
    #pragma unroll
    for (int ww = 1; ww < 4; ++ww) {
      const float ov = mvv[ww][lane];
      const int oi = mii[ww][lane];
      if (ov < v) { v = ov; idx = oi; }
    }
    out_codes[row0 + lane] = (float)idx;
    atomicAdd(&bins[idx], 1);

    // fused gather + STE (np rounding order) + fp64 loss partial; o -> xs for coalescing
    const float4* crow = (const float4*)(codebook + (size_t)idx * DIMS);
    double dacc = 0.0;
    #pragma unroll
    for (int d4 = 0; d4 < 16; ++d4) {
      const float4 q = crow[d4];
      const float4 l = xq[d4];
      float4 o;
      o.x = l.x + (q.x - l.x);
      o.y = l.y + (q.y - l.y);
      o.z = l.z + (q.z - l.z);
      o.w = l.w + (q.w - l.w);
      *(float4*)&xs[lane * XS_STRIDE + d4 * 4] = o;
      const float dx = l.x - q.x, dy = l.y - q.y, dz = l.z - q.z, dw = l.w - q.w;
      dacc += (double)dx * (double)dx;
      dacc += (double)dy * (double)dy;
      dacc += (double)dz * (double)dz;
      dacc += (double)dw * (double)dw;
    }
    #pragma unroll
    for (int off = 32; off > 0; off >>= 1) dacc += __shfl_down(dacc, off);
    if (lane == 0) loss_part[blockIdx.x] = dacc;
  }
  __syncthreads();

  // coalesced out_st write from LDS
  {
    float4* dst = (float4*)out_st + (size_t)row0 * 16;
    #pragma unroll
    for (int p = 0; p < 4; ++p) {
      const int f = p * 256 + t;
      const int r = f >> 4, q4 = f & 15;
      dst[f] = *(const float4*)&xs[r * XS_STRIDE + q4 * 4];
    }
  }
}

// ---------------- K3: reduce loss partials + perplexity + scalar outputs ----------
__global__ __launch_bounds__(512) void vq_finalize(const int* __restrict__ bins,
                                                   const double* __restrict__ loss_part,
                                                   float* __restrict__ out3) {
  __shared__ double red[512];
  __shared__ double redl[512];
  const int t = threadIdx.x;
  const double p = (double)bins[t] / 131072.0;
  red[t] = -p * log(p + 1e-10);
  redl[t] = (loss_part[t] + loss_part[t + 512]) + (loss_part[t + 1024] + loss_part[t + 1536]);
  __syncthreads();
  for (int s = 256; s > 0; s >>= 1) {
    if (t < s) { red[t] += red[t + s]; redl[t] += redl[t + s]; }
    __syncthreads();
  }
  if (t == 0) {
    const double mean = redl[0] / 8388608.0;
    out3[0] = (float)(0.25 * mean);  // commitment * COMMITMENT_COST
    out3[1] = (float)mean;           // codebook_loss (same squares bitwise)
    out3[2] = (float)exp(red[0]);    // perplexity
  }
}

extern "C" void kernel_launch(void* const* d_in, const int* in_sizes, int n_in,
                              void* d_out, int out_size, void* d_ws, size_t ws_size,
                              hipStream_t stream) {
  const float* latents = (const float*)d_in[0];
  const float* codebook = (const float*)d_in[1];

  float* out = (float*)d_out;
  float* out_st = out;                              // 8388608
  float* out_codes = out + (size_t)N_ROWS * DIMS;   // 131072 (codes as float)
  float* out3 = out_codes + N_ROWS;                 // 3 scalars

  char* ws = (char*)d_ws;
  double* loss_part = (double*)ws;                  // [0, 16384)        2048 doubles
  int* bins = (int*)(ws + 16384);                   // [16384, 18432)
  float* c2g = (float*)(ws + 18432);                // [18432, 20480)
  float* cbT2 = (float*)(ws + 20480);               // [20480, 151552)   128 KB transposed

  hipLaunchKernelGGL(vq_init, dim3(64), dim3(256), 0, stream,
                     codebook, bins, c2g, cbT2);
  hipLaunchKernelGGL(vq_main, dim3(NBLK), dim3(256), 0, stream,
                     latents, codebook, cbT2, c2g, out_st, out_codes, bins, loss_part);
  hipLaunchKernelGGL(vq_finalize, dim3(1), dim3(512), 0, stream,
                     bins, loss_part, out3);
}